// Round 1
// baseline (401.289 us; speedup 1.0000x reference)
//
#include <hip/hip_runtime.h>
#include <stdint.h>

#define B_ 64
#define T_ 2048
#define O_ 3
#define D_ 512
#define V_ 128
#define M_ 100000
#define H_ 4
#define HD_ 128

// primes[h][i]: x0 = 131 + h*1009; x_{k+1} = x_k*31 + 1 (no uint32 wrap occurs)
__device__ __constant__ unsigned PRIMES_c[H_][4] = {
  {131u,  4062u,  125923u, 3903614u},
  {1140u, 35341u, 1095572u, 33962733u},
  {2149u, 66620u, 2065221u, 64021852u},
  {3158u, 97899u, 3034870u, 94080971u},
};

template<int CTRL, int RMASK>
__device__ __forceinline__ float dpp_term(float x) {
  return __int_as_float(__builtin_amdgcn_update_dpp(
      0, __float_as_int(x), CTRL, RMASK, 0xF, true));
}

// Full 64-lane sum, broadcast to all lanes. DPP (VALU pipe), no LDS traffic.
__device__ __forceinline__ float wave_sum(float x) {
  x += dpp_term<0xB1, 0xF>(x);   // quad_perm [1,0,3,2]  (xor 1)
  x += dpp_term<0x4E, 0xF>(x);   // quad_perm [2,3,0,1]  (xor 2)
  x += dpp_term<0x141, 0xF>(x);  // row_half_mirror      (xor 4)
  x += dpp_term<0x140, 0xF>(x);  // row_mirror           (xor 8)
  x += dpp_term<0x142, 0xA>(x);  // row_bcast:15 -> rows 1,3
  x += dpp_term<0x143, 0xC>(x);  // row_bcast:31 -> rows 2,3 ; lane63 = total
  return __int_as_float(__builtin_amdgcn_readlane(__float_as_int(x), 63));
}

__device__ __forceinline__ bool read_mask(const void* mb, size_t i, int imode) {
  return imode ? (((const int*)mb)[i] != 0)
               : (((const unsigned char*)mb)[i] != 0);
}

// mask_bool dtype detection: if stored as int32, all 4-byte words are 0/1.
// If stored as 1-byte bools, packed words exceed 1 almost surely.
__global__ void k_detect(const unsigned* __restrict__ m, int nwords,
                         int* __restrict__ flag) {
  __shared__ int bad;
  if (threadIdx.x == 0) bad = 0;
  __syncthreads();
  int loc = 0;
  for (int i = threadIdx.x; i < nwords; i += blockDim.x)
    loc |= (m[i] > 1u) ? 1 : 0;
  if (loc) bad = 1;
  __syncthreads();
  if (threadIdx.x == 0) flag[0] = bad ? 0 : 1;  // 1 = int32 mode
}

template<int TC>
__global__ __launch_bounds__(256) void k_pass1(
    const int* __restrict__ tokens, const int* __restrict__ prev,
    const void* __restrict__ maskbuf, const float* __restrict__ embed,
    const float* __restrict__ engram, const float* __restrict__ gate_logit,
    const float* __restrict__ temp, const float* __restrict__ salW,
    const float* __restrict__ salb, const int* __restrict__ flag,
    float* __restrict__ partials)
{
  const int NCH = T_ / TC;
  int blk = blockIdx.x;
  int b = blk / NCH, c = blk % NCH;
  int t0 = c * TC;
  int tid = threadIdx.x;
  int h = tid >> 6, lane = tid & 63;

  __shared__ int ltok[TC + 3];            // ext tokens: ltok[j] = ext[t0+j]
  __shared__ unsigned eoff[TC * H_];      // engram row float-offset per (t,h)
  __shared__ unsigned char lmask[TC];

  int imode = flag[0];
  for (int j = tid; j < TC + 3; j += 256) {
    int g = t0 + j;
    ltok[j] = (g < O_) ? prev[b * O_ + g] : tokens[(size_t)b * T_ + g - O_];
  }
  for (int j = tid; j < TC; j += 256)
    lmask[j] = read_mask(maskbuf, (size_t)b * T_ + t0 + j, imode) ? 1 : 0;
  __syncthreads();

  // hash precompute: hash_t = sum_i ext[t+3-i] * primes[h][i] (uint32 wrap)
  for (int k = tid; k < TC * H_; k += 256) {
    int j  = k & (TC - 1);
    int hh = k / TC;
    unsigned hs = (unsigned)ltok[j + 3] * PRIMES_c[hh][0]
                + (unsigned)ltok[j + 2] * PRIMES_c[hh][1]
                + (unsigned)ltok[j + 1] * PRIMES_c[hh][2]
                + (unsigned)ltok[j]     * PRIMES_c[hh][3];
    unsigned idx = hs % (unsigned)M_;
    eoff[j * H_ + hh] = idx * (unsigned)(H_ * HD_) + (unsigned)(hh * HD_);
  }
  __syncthreads();

  int d0 = lane * 2;
  int gd = h * HD_ + d0;
  float g0 = 1.f / (1.f + __expf(-gate_logit[gd]));
  float g1 = 1.f / (1.f + __expf(-gate_logit[gd + 1]));
  float w0 = salW[gd * H_ + h];
  float w1 = salW[(gd + 1) * H_ + h];
  float tv = temp[h];
  float sp = (tv > 20.f) ? tv : log1pf(__expf(tv));
  float invT = 1.f / (sp + 0.3f);
  float sb = salb[h];

  float m = -1e30f, s = 0.f, a0 = 0.f, a1 = 0.f;

  #pragma unroll 4
  for (int j = 0; j < TC; ++j) {
    int tokc = ltok[j + 3];
    unsigned eo = eoff[j * H_ + h];
    float2 r = *(const float2*)(engram + eo + d0);
    float2 e = *(const float2*)(embed + tokc * D_ + gd);
    float x0 = fmaf(r.x, g0, e.x);
    float x1 = fmaf(r.y, g1, e.y);
    float pd = x0 * w0 + x1 * w1;
    float dot = wave_sum(pd);
    if (lmask[j]) {
      float logit = (dot + sb) * invT;
      float nm = fmaxf(m, logit);
      float al = __expf(m - nm);
      float w  = __expf(logit - nm);
      s  = fmaf(s,  al, w);
      a0 = fmaf(a0, al, w * x0);
      a1 = fmaf(a1, al, w * x1);
      m = nm;
    }
  }

  float* P = partials + ((size_t)(b * NCH + c) * H_ + h) * (HD_ + 2);
  if (lane == 0) { P[0] = m; P[1] = s; }
  *(float2*)(P + 2 + d0) = make_float2(a0, a1);
}

template<int TC>
__global__ __launch_bounds__(256) void k_pass2(
    const float* __restrict__ partials, const void* __restrict__ maskbuf,
    const int* __restrict__ flag, const float* __restrict__ gateW,
    const float* __restrict__ gateb, const float* __restrict__ rms_scale,
    float* __restrict__ out)
{
  const int NCH = T_ / TC;
  int b = blockIdx.x;
  int tid = threadIdx.x, h = tid >> 6, lane = tid & 63;
  int imode = flag[0];

  __shared__ int s_any;
  __shared__ float s_ss[H_];
  if (tid == 0) s_any = 0;
  __syncthreads();
  int any = 0;
  for (int j = tid; j < T_; j += 256)
    any |= read_mask(maskbuf, (size_t)b * T_ + j, imode) ? 1 : 0;
  if (any) s_any = 1;
  __syncthreads();

  int d0 = lane * 2;
  float M = -1e30f;
  for (int c = 0; c < NCH; ++c) {
    const float* P = partials + ((size_t)(b * NCH + c) * H_ + h) * (HD_ + 2);
    M = fmaxf(M, P[0]);
  }
  float S = 0.f, A0 = 0.f, A1 = 0.f;
  for (int c = 0; c < NCH; ++c) {
    const float* P = partials + ((size_t)(b * NCH + c) * H_ + h) * (HD_ + 2);
    float f = __expf(P[0] - M);
    float2 a = *(const float2*)(P + 2 + d0);
    S  = fmaf(P[1], f, S);
    A0 = fmaf(a.x, f, A0);
    A1 = fmaf(a.y, f, A1);
  }
  float inv = 1.f / (S + 1e-6f);
  float v0 = A0 * inv, v1 = A1 * inv;   // write_vec_heads[b][h][d0, d0+1]

  float pg = v0 * gateW[d0] + v1 * gateW[d0 + 1];
  float ss = v0 * v0 + v1 * v1;
  float gl  = wave_sum(pg);
  float sst = wave_sum(ss);
  if (lane == 0) s_ss[h] = sst;
  __syncthreads();
  float tot = s_ss[0] + s_ss[1] + s_ss[2] + s_ss[3];
  float rinv = rsqrtf(tot / (float)D_ + 1e-6f);
  float u = (1.f / (1.f + __expf(-(gl + gateb[0])))) * (s_any ? 1.f : 0.f);

  int gd = h * HD_ + d0;
  size_t ob = (size_t)b * (2 * D_);
  out[ob + gd]          = v0 * rinv * rms_scale[gd];
  out[ob + gd + 1]      = v1 * rinv * rms_scale[gd + 1];
  out[ob + D_ + gd]     = u;
  out[ob + D_ + gd + 1] = u;
}

extern "C" void kernel_launch(void* const* d_in, const int* in_sizes, int n_in,
                              void* d_out, int out_size, void* d_ws, size_t ws_size,
                              hipStream_t stream)
{
  const int*   tokens     = (const int*)d_in[0];
  const int*   prev       = (const int*)d_in[1];
  const void*  mask       = d_in[2];
  const float* embed      = (const float*)d_in[3];
  const float* engram     = (const float*)d_in[4];
  const float* gate_logit = (const float*)d_in[5];
  const float* temp       = (const float*)d_in[6];
  const float* salW       = (const float*)d_in[7];
  const float* salb       = (const float*)d_in[8];
  const float* gateW      = (const float*)d_in[9];
  const float* gateb      = (const float*)d_in[10];
  const float* rms_scale  = (const float*)d_in[11];
  float* out = (float*)d_out;

  int*   flag     = (int*)d_ws;
  float* partials = (float*)((char*)d_ws + 256);

  k_detect<<<1, 256, 0, stream>>>((const unsigned*)mask, (B_ * T_) / 4, flag);

  size_t need128 = 256 + (size_t)B_ * (T_ / 128) * H_ * (HD_ + 2) * sizeof(float);
  if (ws_size >= need128) {
    k_pass1<128><<<B_ * (T_ / 128), 256, 0, stream>>>(
        tokens, prev, mask, embed, engram, gate_logit, temp, salW, salb,
        flag, partials);
    k_pass2<128><<<B_, 256, 0, stream>>>(
        partials, mask, flag, gateW, gateb, rms_scale, out);
  } else {
    // fallback for a small workspace: fewer, longer chunks
    k_pass1<512><<<B_ * (T_ / 512), 256, 0, stream>>>(
        tokens, prev, mask, embed, engram, gate_logit, temp, salW, salb,
        flag, partials);
    k_pass2<512><<<B_, 256, 0, stream>>>(
        partials, mask, flag, gateW, gateb, rms_scale, out);
  }
}

// Round 2
// 318.166 us; speedup vs baseline: 1.2613x; 1.2613x over previous
//
#include <hip/hip_runtime.h>
#include <stdint.h>

#define B_ 64
#define T_ 2048
#define O_ 3
#define D_ 512
#define V_ 128
#define M_ 100000
#define H_ 4
#define HD_ 128

// primes[h][i]: x0 = 131 + h*1009; x_{k+1} = x_k*31 + 1 (no uint32 wrap occurs)
__device__ __constant__ unsigned PRIMES_c[H_][4] = {
  {131u,  4062u,  125923u, 3903614u},
  {1140u, 35341u, 1095572u, 33962733u},
  {2149u, 66620u, 2065221u, 64021852u},
  {3158u, 97899u, 3034870u, 94080971u},
};

template<int CTRL, int RMASK>
__device__ __forceinline__ float dpp_term(float x) {
  return __int_as_float(__builtin_amdgcn_update_dpp(
      0, __float_as_int(x), CTRL, RMASK, 0xF, true));
}

// Full 64-lane sum, broadcast to all lanes. DPP (VALU pipe), no LDS traffic.
__device__ __forceinline__ float wave_sum(float x) {
  x += dpp_term<0xB1, 0xF>(x);   // quad_perm [1,0,3,2]  (xor 1)
  x += dpp_term<0x4E, 0xF>(x);   // quad_perm [2,3,0,1]  (xor 2)
  x += dpp_term<0x141, 0xF>(x);  // row_half_mirror      (xor 4)
  x += dpp_term<0x140, 0xF>(x);  // row_mirror           (xor 8)
  x += dpp_term<0x142, 0xA>(x);  // row_bcast:15 -> rows 1,3
  x += dpp_term<0x143, 0xC>(x);  // row_bcast:31 -> rows 2,3 ; lane63 = total
  return __int_as_float(__builtin_amdgcn_readlane(__float_as_int(x), 63));
}

__device__ __forceinline__ bool read_mask(const void* mb, size_t i, int imode) {
  return imode ? (((const int*)mb)[i] != 0)
               : (((const unsigned char*)mb)[i] != 0);
}

// Per-block mask dtype detection: wave 0 scans the first 2048 words (8 KB,
// valid in both modes since byte-mode buffer is 128 KB). int32 mode => every
// word is 0/1; byte-mode packed bools exceed 1 with prob 1-8^-2048.
__device__ __forceinline__ void detect_imode(const void* maskbuf, int tid,
                                             int* s_imode) {
  if (tid < 64) {
    const uint4* mw = (const uint4*)maskbuf;
    unsigned bad = 0;
    #pragma unroll
    for (int i = 0; i < 8; ++i) {
      uint4 v = mw[tid + i * 64];
      bad |= (v.x > 1u) | (v.y > 1u) | (v.z > 1u) | (v.w > 1u);
    }
    unsigned long long anybad = __ballot(bad != 0);
    if (tid == 0) *s_imode = (anybad == 0ull) ? 1 : 0;
  }
}

template<int TC>
__global__ __launch_bounds__(256) void k_pass1(
    const int* __restrict__ tokens, const int* __restrict__ prev,
    const void* __restrict__ maskbuf, const float* __restrict__ embed,
    const float* __restrict__ engram, const float* __restrict__ gate_logit,
    const float* __restrict__ temp, const float* __restrict__ salW,
    const float* __restrict__ salb, float* __restrict__ partials)
{
  const int NCH = T_ / TC;
  int blk = blockIdx.x;
  int b = blk / NCH, c = blk % NCH;
  int t0 = c * TC;
  int tid = threadIdx.x;
  int h = tid >> 6, lane = tid & 63;

  __shared__ int s_imode;
  __shared__ int ltok[TC + 3];         // ext tokens: ltok[j] = ext[t0+j]
  __shared__ unsigned eoff[TC * H_];   // engram row float-offset per (act,h)
  __shared__ int s_act[TC];            // compacted active j list
  __shared__ int s_cnt[2];
  __shared__ int s_nact;

  detect_imode(maskbuf, tid, &s_imode);
  for (int j = tid; j < TC + 3; j += 256) {
    int g = t0 + j;
    ltok[j] = (g < O_) ? prev[b * O_ + g] : tokens[(size_t)b * T_ + g - O_];
  }
  __syncthreads();

  int imode = s_imode;
  static_assert(TC == 128, "compaction path assumes TC==128");
  // ballot compaction of active timesteps (threads 0..127 cover j=tid)
  bool act = false;
  unsigned long long bal = 0;
  if (tid < TC) {
    act = read_mask(maskbuf, (size_t)b * T_ + t0 + tid, imode);
    bal = __ballot(act);
    if ((tid & 63) == 0) s_cnt[tid >> 6] = __popcll(bal);
  }
  __syncthreads();
  if (tid < TC) {
    int l = tid & 63;
    int pre = __popcll(bal & ((1ull << l) - 1));
    int base = (tid >> 6) ? s_cnt[0] : 0;
    if (act) s_act[base + pre] = tid;
    if (tid == 0) s_nact = s_cnt[0] + s_cnt[1];
  }
  __syncthreads();
  int nact = s_nact;

  // hash only for active timesteps: eoff[a*H+h]
  for (int k = tid; k < nact * H_; k += 256) {
    int a  = k >> 2;
    int hh = k & 3;
    int j  = s_act[a];
    unsigned hs = (unsigned)ltok[j + 3] * PRIMES_c[hh][0]
                + (unsigned)ltok[j + 2] * PRIMES_c[hh][1]
                + (unsigned)ltok[j + 1] * PRIMES_c[hh][2]
                + (unsigned)ltok[j]     * PRIMES_c[hh][3];
    unsigned idx = hs % (unsigned)M_;
    eoff[k] = idx * (unsigned)(H_ * HD_) + (unsigned)(hh * HD_);
  }
  __syncthreads();

  int d0 = lane * 2;
  int gd = h * HD_ + d0;
  float g0 = 1.f / (1.f + __expf(-gate_logit[gd]));
  float g1 = 1.f / (1.f + __expf(-gate_logit[gd + 1]));
  float w0 = salW[gd * H_ + h];
  float w1 = salW[(gd + 1) * H_ + h];
  float tv = temp[h];
  float sp = (tv > 20.f) ? tv : log1pf(__expf(tv));
  float invT = 1.f / (sp + 0.3f);
  float sb = salb[h];

  float m = -1e30f, s = 0.f, a0 = 0.f, a1 = 0.f;

  #pragma unroll 4
  for (int k = 0; k < nact; ++k) {
    int j = s_act[k];
    int tokc = ltok[j + 3];
    unsigned eo = eoff[k * H_ + h];
    float2 r = *(const float2*)(engram + eo + d0);
    float2 e = *(const float2*)(embed + tokc * D_ + gd);
    float x0 = fmaf(r.x, g0, e.x);
    float x1 = fmaf(r.y, g1, e.y);
    float pd = x0 * w0 + x1 * w1;
    float dot = wave_sum(pd);
    float logit = (dot + sb) * invT;
    if (logit <= m) {               // wave-uniform branch; single exp
      float w = __expf(logit - m);
      s += w;
      a0 = fmaf(w, x0, a0);
      a1 = fmaf(w, x1, a1);
    } else {
      float al = __expf(m - logit);
      s  = fmaf(s,  al, 1.f);
      a0 = fmaf(a0, al, x0);
      a1 = fmaf(a1, al, x1);
      m = logit;
    }
  }

  float* P = partials + ((size_t)(b * NCH + c) * H_ + h) * (HD_ + 2);
  if (lane == 0) { P[0] = m; P[1] = s; }
  *(float2*)(P + 2 + d0) = make_float2(a0, a1);
}

template<int TC>
__global__ __launch_bounds__(256) void k_pass2(
    const float* __restrict__ partials, const void* __restrict__ maskbuf,
    const float* __restrict__ gateW, const float* __restrict__ gateb,
    const float* __restrict__ rms_scale, float* __restrict__ out)
{
  const int NCH = T_ / TC;
  int b = blockIdx.x;
  int tid = threadIdx.x, h = tid >> 6, lane = tid & 63;

  __shared__ int s_imode;
  __shared__ int s_any;
  __shared__ float s_ss[H_];
  if (tid == 0) s_any = 0;
  detect_imode(maskbuf, tid, &s_imode);
  __syncthreads();
  int imode = s_imode;
  int any = 0;
  for (int j = tid; j < T_; j += 256)
    any |= read_mask(maskbuf, (size_t)b * T_ + j, imode) ? 1 : 0;
  if (any) s_any = 1;
  __syncthreads();

  int d0 = lane * 2;
  float M = -1e30f;
  for (int c = 0; c < NCH; ++c) {
    const float* P = partials + ((size_t)(b * NCH + c) * H_ + h) * (HD_ + 2);
    M = fmaxf(M, P[0]);
  }
  float S = 0.f, A0 = 0.f, A1 = 0.f;
  for (int c = 0; c < NCH; ++c) {
    const float* P = partials + ((size_t)(b * NCH + c) * H_ + h) * (HD_ + 2);
    float f = __expf(P[0] - M);
    float2 a = *(const float2*)(P + 2 + d0);
    S  = fmaf(P[1], f, S);
    A0 = fmaf(a.x, f, A0);
    A1 = fmaf(a.y, f, A1);
  }
  float inv = 1.f / (S + 1e-6f);
  float v0 = A0 * inv, v1 = A1 * inv;   // write_vec_heads[b][h][d0, d0+1]

  float pg = v0 * gateW[d0] + v1 * gateW[d0 + 1];
  float ss = v0 * v0 + v1 * v1;
  float gl  = wave_sum(pg);
  float sst = wave_sum(ss);
  if (lane == 0) s_ss[h] = sst;
  __syncthreads();
  float tot = s_ss[0] + s_ss[1] + s_ss[2] + s_ss[3];
  float rinv = rsqrtf(tot / (float)D_ + 1e-6f);
  float u = (1.f / (1.f + __expf(-(gl + gateb[0])))) * (s_any ? 1.f : 0.f);

  int gd = h * HD_ + d0;
  size_t ob = (size_t)b * (2 * D_);
  out[ob + gd]          = v0 * rinv * rms_scale[gd];
  out[ob + gd + 1]      = v1 * rinv * rms_scale[gd + 1];
  out[ob + D_ + gd]     = u;
  out[ob + D_ + gd + 1] = u;
}

extern "C" void kernel_launch(void* const* d_in, const int* in_sizes, int n_in,
                              void* d_out, int out_size, void* d_ws, size_t ws_size,
                              hipStream_t stream)
{
  const int*   tokens     = (const int*)d_in[0];
  const int*   prev       = (const int*)d_in[1];
  const void*  mask       = d_in[2];
  const float* embed      = (const float*)d_in[3];
  const float* engram     = (const float*)d_in[4];
  const float* gate_logit = (const float*)d_in[5];
  const float* temp       = (const float*)d_in[6];
  const float* salW       = (const float*)d_in[7];
  const float* salb       = (const float*)d_in[8];
  const float* gateW      = (const float*)d_in[9];
  const float* gateb      = (const float*)d_in[10];
  const float* rms_scale  = (const float*)d_in[11];
  float* out = (float*)d_out;

  float* partials = (float*)d_ws;

  k_pass1<128><<<B_ * (T_ / 128), 256, 0, stream>>>(
      tokens, prev, mask, embed, engram, gate_logit, temp, salW, salb,
      partials);
  k_pass2<128><<<B_, 256, 0, stream>>>(
      partials, mask, gateW, gateb, rms_scale, out);
}